// Round 4
// baseline (372.187 us; speedup 1.0000x reference)
//
#include <hip/hip_runtime.h>

#define D 64
#define G 10000
#define SCAN_T 1024
#define PER_T 10   // SCAN_T * PER_T >= G

// ---------- K1: histogram of keys (int atomics, 40 KB L2-resident) ----------
__global__ void hist_kernel(const int* __restrict__ keys, int* __restrict__ counts, int n) {
    int stride = gridDim.x * blockDim.x;
    for (int i = blockIdx.x * blockDim.x + threadIdx.x; i < n; i += stride)
        atomicAdd(&counts[keys[i]], 1);
}

// ---------- K2: exclusive prefix sum over G counts (single block) ----------
__global__ void scan_kernel(const int* __restrict__ counts,
                            int* __restrict__ offs, int* __restrict__ cursor) {
    __shared__ int tsum[SCAN_T];
    const int t = threadIdx.x;
    const int base = t * PER_T;
    int local[PER_T];
    int s = 0;
    for (int j = 0; j < PER_T; ++j) {
        int idx = base + j;
        int c = (idx < G) ? counts[idx] : 0;
        local[j] = s;
        s += c;
    }
    tsum[t] = s;
    __syncthreads();
    for (int off = 1; off < SCAN_T; off <<= 1) {
        int v = (t >= off) ? tsum[t - off] : 0;
        __syncthreads();
        tsum[t] += v;
        __syncthreads();
    }
    const int prev = (t > 0) ? tsum[t - 1] : 0;
    for (int j = 0; j < PER_T; ++j) {
        int idx = base + j;
        if (idx < G) {
            int o = prev + local[j];
            offs[idx]   = o;
            cursor[idx] = o;
        }
    }
}

// ---------- K3: scatter row ids into per-group contiguous lists ----------
__global__ void scatter_kernel(const int* __restrict__ keys, int* __restrict__ cursor,
                               int* __restrict__ rowids, int n) {
    int stride = gridDim.x * blockDim.x;
    for (int i = blockIdx.x * blockDim.x + threadIdx.x; i < n; i += stride) {
        int pos = atomicAdd(&cursor[keys[i]], 1);
        rowids[pos] = i;
    }
}

// ---------- K4: one wave per group; float4 lanes; writes only 5 MB stats ----
// Lane layout: lane l owns dims [(l&15)*4, +4) of row-subgroup (l>>4).
__global__ void reduce_stats_kernel(const int* __restrict__ rowids,
                                    const int* __restrict__ offs,
                                    const int* __restrict__ counts,
                                    const float* __restrict__ emb,
                                    float* __restrict__ mean_g,
                                    float* __restrict__ var_g) {
    const int wave = (blockIdx.x * blockDim.x + threadIdx.x) >> 6;
    const int lane = threadIdx.x & 63;
    if (wave >= G) return;
    const int n = counts[wave];
    if (n == 0) return;
    const int base = offs[wave];
    const int sub   = lane >> 4;
    const int dbase = (lane & 15) << 2;

    float s[4] = {0.f, 0.f, 0.f, 0.f};
    float q[4] = {0.f, 0.f, 0.f, 0.f};

    for (int j0 = 0; j0 < n; j0 += 64) {
        const int m = min(64, n - j0);
        int rid = (lane < m) ? rowids[base + j0 + lane] : 0;
        const int iters = (m + 3) >> 2;
        for (int jj = 0; jj < iters; ++jj) {
            const int j = (jj << 2) + sub;
            const int r = __shfl(rid, j);
            if (j < m) {
                const float4 v = *reinterpret_cast<const float4*>(
                    emb + (size_t)r * D + dbase);
                s[0] += v.x; s[1] += v.y; s[2] += v.z; s[3] += v.w;
                q[0] += v.x * v.x; q[1] += v.y * v.y;
                q[2] += v.z * v.z; q[3] += v.w * v.w;
            }
        }
    }
#pragma unroll
    for (int k = 0; k < 4; ++k) {
        s[k] += __shfl_xor(s[k], 16);
        q[k] += __shfl_xor(q[k], 16);
        s[k] += __shfl_xor(s[k], 32);
        q[k] += __shfl_xor(q[k], 32);
    }
    if (sub == 0) {
        const float inv = 1.0f / (float)n;
        float4 mean, var;
        mean.x = s[0] * inv; mean.y = s[1] * inv;
        mean.z = s[2] * inv; mean.w = s[3] * inv;
        var.x = q[0] * inv - mean.x * mean.x;
        var.y = q[1] * inv - mean.y * mean.y;
        var.z = q[2] * inv - mean.z * mean.z;
        var.w = q[3] * inv - mean.w * mean.w;   // biased (tf.nn.moments)
        const size_t gi = (size_t)wave * D + dbase;
        *reinterpret_cast<float4*>(mean_g + gi) = mean;
        *reinterpret_cast<float4*>(var_g  + gi) = var;
    }
}

// ---------- K5: row-ordered gather — sequential 512 MB writes --------------
// Wave handles 4 consecutive rows; lane l: row base+(l>>4), dims (l&15)*4.
// Stats (5 MB) are L2-resident; writes are fully coalesced & sequential.
__global__ void gather_kernel(const int* __restrict__ keys,
                              const float* __restrict__ mean_g,
                              const float* __restrict__ var_g,
                              float* __restrict__ out, int n_rows) {
    const long long wave_id = ((long long)blockIdx.x * blockDim.x + threadIdx.x) >> 6;
    const int lane = threadIdx.x & 63;
    const long long nwaves = ((long long)n_rows + 3) >> 2;
    const long long wstride = ((long long)gridDim.x * blockDim.x) >> 6;
    const size_t var_off = (size_t)n_rows * D;
    const int dbase = (lane & 15) << 2;
    for (long long w = wave_id; w < nwaves; w += wstride) {
        const int row = (int)((w << 2) + (lane >> 4));
        if (row < n_rows) {
            const int key = keys[row];
            const size_t gi = (size_t)key * D + dbase;
            const float4 m = *reinterpret_cast<const float4*>(mean_g + gi);
            const float4 v = *reinterpret_cast<const float4*>(var_g + gi);
            float* p = out + (size_t)row * D + dbase;
            *reinterpret_cast<float4*>(p)           = m;
            *reinterpret_cast<float4*>(p + var_off) = v;
        }
    }
}

extern "C" void kernel_launch(void* const* d_in, const int* in_sizes, int n_in,
                              void* d_out, int out_size, void* d_ws, size_t ws_size,
                              hipStream_t stream) {
    const int* keys  = (const int*)d_in[0];
    const float* emb = (const float*)d_in[1];
    float* out = (float*)d_out;
    const int n_rows = in_sizes[0];

    // Workspace: counts[G] | offs[G] | cursor[G] | rowids[N] | mean_g[G*D] | var_g[G*D]
    int* counts = (int*)d_ws;
    int* offs   = counts + G;
    int* cursor = offs + G;
    int* rowids = cursor + G;
    float* mean_g = (float*)(rowids + n_rows);
    float* var_g  = mean_g + (size_t)G * D;

    // counts must be zero each call (d_ws poisoned once, never re-poisoned).
    hipMemsetAsync(counts, 0, G * sizeof(int), stream);

    const int block = 256;
    int grid_n = (n_rows + block - 1) / block;
    if (grid_n > 4096) grid_n = 4096;

    hist_kernel<<<grid_n, block, 0, stream>>>(keys, counts, n_rows);
    scan_kernel<<<1, SCAN_T, 0, stream>>>(counts, offs, cursor);
    scatter_kernel<<<grid_n, block, 0, stream>>>(keys, cursor, rowids, n_rows);

    const int red_grid = (G * 64) / block;   // one 64-lane wave per group
    reduce_stats_kernel<<<red_grid, block, 0, stream>>>(rowids, offs, counts,
                                                        emb, mean_g, var_g);

    const long long nwaves = ((long long)n_rows + 3) >> 2;   // 4 rows per wave
    long long gblocks = (nwaves + 3) / 4;                    // 4 waves per block
    int grid_gather = (int)(gblocks > 8192 ? 8192 : gblocks);
    gather_kernel<<<grid_gather, block, 0, stream>>>(keys, mean_g, var_g, out, n_rows);
}

// Round 5
// 304.977 us; speedup vs baseline: 1.2204x; 1.2204x over previous
//
#include <hip/hip_runtime.h>

#define D 64
#define G 10000
#define SCAN_T 1024
#define PER_T 10   // SCAN_T * PER_T >= G

typedef float vf4 __attribute__((ext_vector_type(4)));

// ---------- K1: histogram of keys (int atomics, 40 KB L2-resident) ----------
__global__ void hist_kernel(const int* __restrict__ keys, int* __restrict__ counts, int n) {
    int stride = gridDim.x * blockDim.x;
    for (int i = blockIdx.x * blockDim.x + threadIdx.x; i < n; i += stride)
        atomicAdd(&counts[keys[i]], 1);
}

// ---------- K2: exclusive prefix sum over G counts (single block) ----------
__global__ void scan_kernel(const int* __restrict__ counts,
                            int* __restrict__ offs, int* __restrict__ cursor) {
    __shared__ int tsum[SCAN_T];
    const int t = threadIdx.x;
    const int base = t * PER_T;
    int local[PER_T];
    int s = 0;
    for (int j = 0; j < PER_T; ++j) {
        int idx = base + j;
        int c = (idx < G) ? counts[idx] : 0;
        local[j] = s;
        s += c;
    }
    tsum[t] = s;
    __syncthreads();
    for (int off = 1; off < SCAN_T; off <<= 1) {
        int v = (t >= off) ? tsum[t - off] : 0;
        __syncthreads();
        tsum[t] += v;
        __syncthreads();
    }
    const int prev = (t > 0) ? tsum[t - 1] : 0;
    for (int j = 0; j < PER_T; ++j) {
        int idx = base + j;
        if (idx < G) {
            int o = prev + local[j];
            offs[idx]   = o;
            cursor[idx] = o;
        }
    }
}

// ---------- K3: scatter row ids into per-group contiguous lists ----------
__global__ void scatter_kernel(const int* __restrict__ keys, int* __restrict__ cursor,
                               int* __restrict__ rowids, int n) {
    int stride = gridDim.x * blockDim.x;
    for (int i = blockIdx.x * blockDim.x + threadIdx.x; i < n; i += stride) {
        int pos = atomicAdd(&cursor[keys[i]], 1);
        rowids[pos] = i;
    }
}

// ---------- K4: fused reduce + stat-scatter, MLP-restructured ---------------
// Lane layout: lane l owns dims [(l&15)*4, +4) of row-subgroup (l>>4).
// Full 64-row chunks are branch-free and fully unrolled -> ~16 independent
// nontemporal float4 loads in flight per wave (vs ~1 in the predicated loop).
__global__ void reduce_write_kernel(const int* __restrict__ rowids,
                                    const int* __restrict__ offs,
                                    const int* __restrict__ counts,
                                    const float* __restrict__ emb,
                                    float* __restrict__ out, int n_rows) {
    const int wave = (blockIdx.x * blockDim.x + threadIdx.x) >> 6;
    const int lane = threadIdx.x & 63;
    if (wave >= G) return;
    const int n = counts[wave];
    if (n == 0) return;                  // empty group: never gathered
    const int base  = offs[wave];
    const int sub   = lane >> 4;         // which of 4 concurrent rows
    const int dbase = (lane & 15) << 2;  // this lane's dim base

    float s[4] = {0.f, 0.f, 0.f, 0.f};
    float q[4] = {0.f, 0.f, 0.f, 0.f};

    const int nfull = n >> 6;            // full 64-row chunks
    for (int c = 0; c < nfull; ++c) {
        const int rid = rowids[base + (c << 6) + lane];   // coalesced 256 B
#pragma unroll
        for (int jj = 0; jj < 16; ++jj) {
            const int r = __shfl(rid, (jj << 2) + sub);
            const vf4 v = __builtin_nontemporal_load(
                reinterpret_cast<const vf4*>(emb + (size_t)r * D + dbase));
            s[0] += v.x; s[1] += v.y; s[2] += v.z; s[3] += v.w;
            q[0] += v.x * v.x; q[1] += v.y * v.y;
            q[2] += v.z * v.z; q[3] += v.w * v.w;
        }
    }
    const int m = n & 63;                // tail rows
    if (m) {
        const int tbase = base + (nfull << 6);
        int rid = (lane < m) ? rowids[tbase + lane] : 0;
        const int iters = (m + 3) >> 2;
        for (int jj = 0; jj < iters; ++jj) {
            const int j = (jj << 2) + sub;
            const int r = __shfl(rid, j);
            if (j < m) {
                const vf4 v = __builtin_nontemporal_load(
                    reinterpret_cast<const vf4*>(emb + (size_t)r * D + dbase));
                s[0] += v.x; s[1] += v.y; s[2] += v.z; s[3] += v.w;
                q[0] += v.x * v.x; q[1] += v.y * v.y;
                q[2] += v.z * v.z; q[3] += v.w * v.w;
            }
        }
    }
    // Combine the 4 row-subgroups; afterwards ALL lanes hold the group totals
    // for their dim slot (xor 16 then 32 makes the value uniform across sub).
#pragma unroll
    for (int k = 0; k < 4; ++k) {
        s[k] += __shfl_xor(s[k], 16);
        q[k] += __shfl_xor(q[k], 16);
        s[k] += __shfl_xor(s[k], 32);
        q[k] += __shfl_xor(q[k], 32);
    }
    const float inv = 1.0f / (float)n;
    vf4 mean, var;
    mean.x = s[0] * inv; mean.y = s[1] * inv;
    mean.z = s[2] * inv; mean.w = s[3] * inv;
    var.x = q[0] * inv - mean.x * mean.x;
    var.y = q[1] * inv - mean.y * mean.y;
    var.z = q[2] * inv - mean.z * mean.z;
    var.w = q[3] * inv - mean.w * mean.w;   // biased, matches tf.nn.moments

    const size_t var_off = (size_t)n_rows * D;
    // Scatter stats back to every row; nontemporal (write-once, no L2 alloc).
    for (int c = 0; c < nfull; ++c) {
        const int rid = rowids[base + (c << 6) + lane];   // L2-hot re-read
#pragma unroll
        for (int jj = 0; jj < 16; ++jj) {
            const int r = __shfl(rid, (jj << 2) + sub);
            float* p = out + (size_t)r * D + dbase;
            __builtin_nontemporal_store(mean, reinterpret_cast<vf4*>(p));
            __builtin_nontemporal_store(var,  reinterpret_cast<vf4*>(p + var_off));
        }
    }
    if (m) {
        const int tbase = base + (nfull << 6);
        int rid = (lane < m) ? rowids[tbase + lane] : 0;
        const int iters = (m + 3) >> 2;
        for (int jj = 0; jj < iters; ++jj) {
            const int j = (jj << 2) + sub;
            const int r = __shfl(rid, j);
            if (j < m) {
                float* p = out + (size_t)r * D + dbase;
                __builtin_nontemporal_store(mean, reinterpret_cast<vf4*>(p));
                __builtin_nontemporal_store(var,  reinterpret_cast<vf4*>(p + var_off));
            }
        }
    }
}

extern "C" void kernel_launch(void* const* d_in, const int* in_sizes, int n_in,
                              void* d_out, int out_size, void* d_ws, size_t ws_size,
                              hipStream_t stream) {
    const int* keys  = (const int*)d_in[0];
    const float* emb = (const float*)d_in[1];
    float* out = (float*)d_out;
    const int n_rows = in_sizes[0];

    // Workspace: counts[G] | offs[G] | cursor[G] | rowids[N]   (~4.1 MB)
    int* counts = (int*)d_ws;
    int* offs   = counts + G;
    int* cursor = offs + G;
    int* rowids = cursor + G;

    // counts must be zero each call (d_ws poisoned once, never re-poisoned).
    hipMemsetAsync(counts, 0, G * sizeof(int), stream);

    const int block = 256;
    int grid_n = (n_rows + block - 1) / block;
    if (grid_n > 4096) grid_n = 4096;

    hist_kernel<<<grid_n, block, 0, stream>>>(keys, counts, n_rows);
    scan_kernel<<<1, SCAN_T, 0, stream>>>(counts, offs, cursor);
    scatter_kernel<<<grid_n, block, 0, stream>>>(keys, cursor, rowids, n_rows);

    const int red_grid = (G * 64) / block;   // one 64-lane wave per group
    reduce_write_kernel<<<red_grid, block, 0, stream>>>(rowids, offs, counts,
                                                        emb, out, n_rows);
}

// Round 6
// 300.011 us; speedup vs baseline: 1.2406x; 1.0165x over previous
//
#include <hip/hip_runtime.h>

#define D 64
#define G 10000
#define SCAN_T 1024
#define PER_T 10   // SCAN_T * PER_T >= G

typedef float vf4 __attribute__((ext_vector_type(4)));

// ---------- K1: histogram of keys (int atomics, 40 KB L2-resident) ----------
__global__ void hist_kernel(const int* __restrict__ keys, int* __restrict__ counts, int n) {
    int stride = gridDim.x * blockDim.x;
    for (int i = blockIdx.x * blockDim.x + threadIdx.x; i < n; i += stride)
        atomicAdd(&counts[keys[i]], 1);
}

// ---------- K2: exclusive prefix sum over G counts (single block) ----------
__global__ void scan_kernel(const int* __restrict__ counts,
                            int* __restrict__ offs, int* __restrict__ cursor) {
    __shared__ int tsum[SCAN_T];
    const int t = threadIdx.x;
    const int base = t * PER_T;
    int local[PER_T];
    int s = 0;
    for (int j = 0; j < PER_T; ++j) {
        int idx = base + j;
        int c = (idx < G) ? counts[idx] : 0;
        local[j] = s;
        s += c;
    }
    tsum[t] = s;
    __syncthreads();
    for (int off = 1; off < SCAN_T; off <<= 1) {
        int v = (t >= off) ? tsum[t - off] : 0;
        __syncthreads();
        tsum[t] += v;
        __syncthreads();
    }
    const int prev = (t > 0) ? tsum[t - 1] : 0;
    for (int j = 0; j < PER_T; ++j) {
        int idx = base + j;
        if (idx < G) {
            int o = prev + local[j];
            offs[idx]   = o;
            cursor[idx] = o;
        }
    }
}

// ---------- K3: scatter row ids into per-group contiguous lists ----------
__global__ void scatter_kernel(const int* __restrict__ keys, int* __restrict__ cursor,
                               int* __restrict__ rowids, int n) {
    int stride = gridDim.x * blockDim.x;
    for (int i = blockIdx.x * blockDim.x + threadIdx.x; i < n; i += stride) {
        int pos = atomicAdd(&cursor[keys[i]], 1);
        rowids[pos] = i;
    }
}

// ---------- K4: reduce -> 5 MB group stats; branch-free unrolled MLP --------
// Lane layout: lane l owns dims [(l&15)*4, +4) of row-subgroup (l>>4).
// Full 64-row chunks: 16 independent nontemporal float4 loads in flight.
__global__ void reduce_stats_kernel(const int* __restrict__ rowids,
                                    const int* __restrict__ offs,
                                    const int* __restrict__ counts,
                                    const float* __restrict__ emb,
                                    float* __restrict__ mean_g,
                                    float* __restrict__ var_g) {
    const int wave = (blockIdx.x * blockDim.x + threadIdx.x) >> 6;
    const int lane = threadIdx.x & 63;
    if (wave >= G) return;
    const int n = counts[wave];
    if (n == 0) return;                  // empty group: never gathered
    const int base  = offs[wave];
    const int sub   = lane >> 4;         // which of 4 concurrent rows
    const int dbase = (lane & 15) << 2;  // this lane's dim base

    float s[4] = {0.f, 0.f, 0.f, 0.f};
    float q[4] = {0.f, 0.f, 0.f, 0.f};

    const int nfull = n >> 6;            // full 64-row chunks
    for (int c = 0; c < nfull; ++c) {
        const int rid = rowids[base + (c << 6) + lane];   // coalesced 256 B
#pragma unroll
        for (int jj = 0; jj < 16; ++jj) {
            const int r = __shfl(rid, (jj << 2) + sub);
            const vf4 v = __builtin_nontemporal_load(
                reinterpret_cast<const vf4*>(emb + (size_t)r * D + dbase));
            s[0] += v.x; s[1] += v.y; s[2] += v.z; s[3] += v.w;
            q[0] += v.x * v.x; q[1] += v.y * v.y;
            q[2] += v.z * v.z; q[3] += v.w * v.w;
        }
    }
    const int m = n & 63;                // tail rows
    if (m) {
        const int tbase = base + (nfull << 6);
        int rid = (lane < m) ? rowids[tbase + lane] : 0;
        const int iters = (m + 3) >> 2;
        for (int jj = 0; jj < iters; ++jj) {
            const int j = (jj << 2) + sub;
            const int r = __shfl(rid, j);
            if (j < m) {
                const vf4 v = __builtin_nontemporal_load(
                    reinterpret_cast<const vf4*>(emb + (size_t)r * D + dbase));
                s[0] += v.x; s[1] += v.y; s[2] += v.z; s[3] += v.w;
                q[0] += v.x * v.x; q[1] += v.y * v.y;
                q[2] += v.z * v.z; q[3] += v.w * v.w;
            }
        }
    }
    // Combine the 4 row-subgroups (xor 16, 32): totals uniform across sub.
#pragma unroll
    for (int k = 0; k < 4; ++k) {
        s[k] += __shfl_xor(s[k], 16);
        q[k] += __shfl_xor(q[k], 16);
        s[k] += __shfl_xor(s[k], 32);
        q[k] += __shfl_xor(q[k], 32);
    }
    if (sub == 0) {
        const float inv = 1.0f / (float)n;
        vf4 mean, var;
        mean.x = s[0] * inv; mean.y = s[1] * inv;
        mean.z = s[2] * inv; mean.w = s[3] * inv;
        var.x = q[0] * inv - mean.x * mean.x;
        var.y = q[1] * inv - mean.y * mean.y;
        var.z = q[2] * inv - mean.z * mean.z;
        var.w = q[3] * inv - mean.w * mean.w;   // biased (tf.nn.moments)
        const size_t gi = (size_t)wave * D + dbase;
        *reinterpret_cast<vf4*>(mean_g + gi) = mean;
        *reinterpret_cast<vf4*>(var_g  + gi) = var;
    }
}

// ---------- K5: row-ordered gather — sequential nontemporal 512 MB writes ---
// Wave = 4 consecutive rows; lane l: row w*4+(l>>4), dims (l&15)*4.
// Stats are cached (L2-resident); output writes bypass L2 (write-once).
__global__ void gather_kernel(const int* __restrict__ keys,
                              const float* __restrict__ mean_g,
                              const float* __restrict__ var_g,
                              float* __restrict__ out, int n_rows) {
    const long long wave_id = ((long long)blockIdx.x * blockDim.x + threadIdx.x) >> 6;
    const int lane = threadIdx.x & 63;
    const long long nwaves = ((long long)n_rows + 3) >> 2;
    const long long wstride = ((long long)gridDim.x * blockDim.x) >> 6;
    const size_t var_off = (size_t)n_rows * D;
    const int dbase = (lane & 15) << 2;
    for (long long w = wave_id; w < nwaves; w += wstride) {
        const int row = (int)((w << 2) + (lane >> 4));
        if (row < n_rows) {
            const int key = keys[row];
            const size_t gi = (size_t)key * D + dbase;
            const vf4 m = *reinterpret_cast<const vf4*>(mean_g + gi);
            const vf4 v = *reinterpret_cast<const vf4*>(var_g + gi);
            float* p = out + (size_t)row * D + dbase;
            __builtin_nontemporal_store(m, reinterpret_cast<vf4*>(p));
            __builtin_nontemporal_store(v, reinterpret_cast<vf4*>(p + var_off));
        }
    }
}

extern "C" void kernel_launch(void* const* d_in, const int* in_sizes, int n_in,
                              void* d_out, int out_size, void* d_ws, size_t ws_size,
                              hipStream_t stream) {
    const int* keys  = (const int*)d_in[0];
    const float* emb = (const float*)d_in[1];
    float* out = (float*)d_out;
    const int n_rows = in_sizes[0];

    // Workspace: counts[G] | offs[G] | cursor[G] | rowids[N] | mean_g[G*D] | var_g[G*D]
    int* counts = (int*)d_ws;
    int* offs   = counts + G;
    int* cursor = offs + G;
    int* rowids = cursor + G;
    float* mean_g = (float*)(rowids + n_rows);
    float* var_g  = mean_g + (size_t)G * D;

    // counts must be zero each call (d_ws poisoned once, never re-poisoned).
    hipMemsetAsync(counts, 0, G * sizeof(int), stream);

    const int block = 256;
    int grid_n = (n_rows + block - 1) / block;
    if (grid_n > 4096) grid_n = 4096;

    hist_kernel<<<grid_n, block, 0, stream>>>(keys, counts, n_rows);
    scan_kernel<<<1, SCAN_T, 0, stream>>>(counts, offs, cursor);
    scatter_kernel<<<grid_n, block, 0, stream>>>(keys, cursor, rowids, n_rows);

    const int red_grid = (G * 64) / block;   // one 64-lane wave per group
    reduce_stats_kernel<<<red_grid, block, 0, stream>>>(rowids, offs, counts,
                                                        emb, mean_g, var_g);

    const long long nwaves = ((long long)n_rows + 3) >> 2;   // 4 rows per wave
    long long gblocks = (nwaves + 3) / 4;                    // 4 waves per block
    int grid_gather = (int)(gblocks > 8192 ? 8192 : gblocks);
    gather_kernel<<<grid_gather, block, 0, stream>>>(keys, mean_g, var_g, out, n_rows);
}

// Round 7
// 290.232 us; speedup vs baseline: 1.2824x; 1.0337x over previous
//
#include <hip/hip_runtime.h>

#define D 64
#define G 10000
#define SCAN_T 1024
#define PER_T 10   // SCAN_T * PER_T >= G

typedef float vf4 __attribute__((ext_vector_type(4)));
typedef int   vi4 __attribute__((ext_vector_type(4)));

// ---------- K1: histogram of keys (int4 loads, L2-resident atomics) ---------
__global__ void hist_kernel(const int* __restrict__ keys, int* __restrict__ counts, int n) {
    const int stride = gridDim.x * blockDim.x;
    const int n4 = n >> 2;
    const vi4* k4 = reinterpret_cast<const vi4*>(keys);
    for (int i = blockIdx.x * blockDim.x + threadIdx.x; i < n4; i += stride) {
        const vi4 k = k4[i];
        atomicAdd(&counts[k.x], 1);
        atomicAdd(&counts[k.y], 1);
        atomicAdd(&counts[k.z], 1);
        atomicAdd(&counts[k.w], 1);
    }
    if (blockIdx.x == 0 && threadIdx.x < (n & 3))
        atomicAdd(&counts[keys[(n4 << 2) + threadIdx.x]], 1);
}

// ---------- K2: exclusive prefix sum over G counts (single block) ----------
__global__ void scan_kernel(const int* __restrict__ counts,
                            int* __restrict__ offs, int* __restrict__ cursor) {
    __shared__ int tsum[SCAN_T];
    const int t = threadIdx.x;
    const int base = t * PER_T;
    int local[PER_T];
    int s = 0;
    for (int j = 0; j < PER_T; ++j) {
        int idx = base + j;
        int c = (idx < G) ? counts[idx] : 0;
        local[j] = s;
        s += c;
    }
    tsum[t] = s;
    __syncthreads();
    for (int off = 1; off < SCAN_T; off <<= 1) {
        int v = (t >= off) ? tsum[t - off] : 0;
        __syncthreads();
        tsum[t] += v;
        __syncthreads();
    }
    const int prev = (t > 0) ? tsum[t - 1] : 0;
    for (int j = 0; j < PER_T; ++j) {
        int idx = base + j;
        if (idx < G) {
            int o = prev + local[j];
            offs[idx]   = o;
            cursor[idx] = o;
        }
    }
}

// ---------- K3: scatter row ids into per-group contiguous lists ----------
__global__ void scatter_kernel(const int* __restrict__ keys, int* __restrict__ cursor,
                               int* __restrict__ rowids, int n) {
    const int stride = gridDim.x * blockDim.x;
    const int n4 = n >> 2;
    const vi4* k4 = reinterpret_cast<const vi4*>(keys);
    for (int i = blockIdx.x * blockDim.x + threadIdx.x; i < n4; i += stride) {
        const vi4 k = k4[i];
        const int r = i << 2;
        rowids[atomicAdd(&cursor[k.x], 1)] = r;
        rowids[atomicAdd(&cursor[k.y], 1)] = r + 1;
        rowids[atomicAdd(&cursor[k.z], 1)] = r + 2;
        rowids[atomicAdd(&cursor[k.w], 1)] = r + 3;
    }
    if (blockIdx.x == 0 && threadIdx.x < (n & 3)) {
        const int r = (n4 << 2) + threadIdx.x;
        rowids[atomicAdd(&cursor[keys[r]], 1)] = r;
    }
}

// ---------- K4: reduce -> interleaved stats; branch-free weighted tail ------
// Lane layout: lane l owns dims [(l&15)*4, +4) of row-subgroup (l>>4).
// stat_g[g*128 .. +63] = mean, [+64 .. +127] = var.
__global__ void reduce_stats_kernel(const int* __restrict__ rowids,
                                    const int* __restrict__ offs,
                                    const int* __restrict__ counts,
                                    const float* __restrict__ emb,
                                    float* __restrict__ stat_g) {
    const int wave = (blockIdx.x * blockDim.x + threadIdx.x) >> 6;
    const int lane = threadIdx.x & 63;
    if (wave >= G) return;
    const int n = counts[wave];
    if (n == 0) return;                  // empty group: never gathered
    const int base  = offs[wave];
    const int sub   = lane >> 4;
    const int dbase = (lane & 15) << 2;

    float s[4] = {0.f, 0.f, 0.f, 0.f};
    float q[4] = {0.f, 0.f, 0.f, 0.f};

    const int nfull = n >> 6;            // full 64-row chunks, branch-free
    for (int c = 0; c < nfull; ++c) {
        const int rid = rowids[base + (c << 6) + lane];   // coalesced 256 B
#pragma unroll
        for (int jj = 0; jj < 16; ++jj) {
            const int r = __shfl(rid, (jj << 2) + sub);
            const vf4 v = __builtin_nontemporal_load(
                reinterpret_cast<const vf4*>(emb + (size_t)r * D + dbase));
            s[0] += v.x; s[1] += v.y; s[2] += v.z; s[3] += v.w;
            q[0] += v.x * v.x; q[1] += v.y * v.y;
            q[2] += v.z * v.z; q[3] += v.w * v.w;
        }
    }
    const int m = n & 63;                // tail rows, weighted branch-free
    if (m) {
        const int tbase = base + (nfull << 6);
        // Clamped index: lanes >= m re-load a valid row; weight zeroes it.
        const int rid = rowids[tbase + ((lane < m) ? lane : 0)];
        for (int j0 = 0; j0 < m; j0 += 16) {
#pragma unroll
            for (int u = 0; u < 4; ++u) {
                const int j = j0 + (u << 2) + sub;        // <= 63 always
                const int r = __shfl(rid, j);
                const float w = (j < m) ? 1.0f : 0.0f;
                const vf4 v = __builtin_nontemporal_load(
                    reinterpret_cast<const vf4*>(emb + (size_t)r * D + dbase));
                const float tx = v.x * w, ty = v.y * w, tz = v.z * w, tw = v.w * w;
                s[0] += tx; s[1] += ty; s[2] += tz; s[3] += tw;
                q[0] = fmaf(tx, v.x, q[0]); q[1] = fmaf(ty, v.y, q[1]);
                q[2] = fmaf(tz, v.z, q[2]); q[3] = fmaf(tw, v.w, q[3]);
            }
        }
    }
    // Combine the 4 row-subgroups (xor 16, 32): totals uniform across sub.
#pragma unroll
    for (int k = 0; k < 4; ++k) {
        s[k] += __shfl_xor(s[k], 16);
        q[k] += __shfl_xor(q[k], 16);
        s[k] += __shfl_xor(s[k], 32);
        q[k] += __shfl_xor(q[k], 32);
    }
    if (sub == 0) {
        const float inv = 1.0f / (float)n;
        vf4 mean, var;
        mean.x = s[0] * inv; mean.y = s[1] * inv;
        mean.z = s[2] * inv; mean.w = s[3] * inv;
        var.x = q[0] * inv - mean.x * mean.x;
        var.y = q[1] * inv - mean.y * mean.y;
        var.z = q[2] * inv - mean.z * mean.z;
        var.w = q[3] * inv - mean.w * mean.w;   // biased (tf.nn.moments)
        float* sp = stat_g + (size_t)wave * 128 + dbase;
        *reinterpret_cast<vf4*>(sp)      = mean;
        *reinterpret_cast<vf4*>(sp + 64) = var;
    }
}

// ---------- K5: gather — 16 rows/wave, unrolled; sequential NT writes -------
// Wave = 16 consecutive rows (4 unrolled quads); lane l: row +u*4+(l>>4),
// dims (l&15)*4. All loads issued before stores for queue depth.
__global__ void gather_kernel(const int* __restrict__ keys,
                              const float* __restrict__ stat_g,
                              float* __restrict__ out, int n_rows) {
    const long long wave = ((long long)blockIdx.x * blockDim.x + threadIdx.x) >> 6;
    const int lane = threadIdx.x & 63;
    const int sub   = lane >> 4;
    const int dbase = (lane & 15) << 2;
    const size_t var_off = (size_t)n_rows * D;
    const long long rowbase = wave << 4;
    if (rowbase >= n_rows) return;

    vf4 mv[4], vv[4];
#pragma unroll
    for (int u = 0; u < 4; ++u) {
        int row = (int)rowbase + (u << 2) + sub;
        row = min(row, n_rows - 1);              // tail clamp (stores guarded)
        const int key = keys[row];
        const float* sp = stat_g + (size_t)key * 128 + dbase;
        mv[u] = *reinterpret_cast<const vf4*>(sp);
        vv[u] = *reinterpret_cast<const vf4*>(sp + 64);
    }
#pragma unroll
    for (int u = 0; u < 4; ++u) {
        const int row = (int)rowbase + (u << 2) + sub;
        if (row < n_rows) {
            float* p = out + (size_t)row * D + dbase;
            __builtin_nontemporal_store(mv[u], reinterpret_cast<vf4*>(p));
            __builtin_nontemporal_store(vv[u], reinterpret_cast<vf4*>(p + var_off));
        }
    }
}

extern "C" void kernel_launch(void* const* d_in, const int* in_sizes, int n_in,
                              void* d_out, int out_size, void* d_ws, size_t ws_size,
                              hipStream_t stream) {
    const int* keys  = (const int*)d_in[0];
    const float* emb = (const float*)d_in[1];
    float* out = (float*)d_out;
    const int n_rows = in_sizes[0];

    // Workspace: counts[G] | offs[G] | cursor[G] | rowids[N] | stat_g[G*128]
    // stat_g byte offset = (3G + N)*4 = 4,120,000 — 16B-aligned.
    int* counts = (int*)d_ws;
    int* offs   = counts + G;
    int* cursor = offs + G;
    int* rowids = cursor + G;
    float* stat_g = (float*)(rowids + n_rows);

    // counts must be zero each call (d_ws poisoned once, never re-poisoned).
    hipMemsetAsync(counts, 0, G * sizeof(int), stream);

    const int block = 256;
    int grid_n = ((n_rows >> 2) + block - 1) / block;
    if (grid_n > 2048) grid_n = 2048;

    hist_kernel<<<grid_n, block, 0, stream>>>(keys, counts, n_rows);
    scan_kernel<<<1, SCAN_T, 0, stream>>>(counts, offs, cursor);
    scatter_kernel<<<grid_n, block, 0, stream>>>(keys, cursor, rowids, n_rows);

    const int red_grid = (G * 64) / block;   // one 64-lane wave per group
    reduce_stats_kernel<<<red_grid, block, 0, stream>>>(rowids, offs, counts,
                                                        emb, stat_g);

    const long long nwaves = ((long long)n_rows + 15) >> 4;  // 16 rows per wave
    const int grid_gather = (int)((nwaves + 3) / 4);         // 4 waves per block
    gather_kernel<<<grid_gather, block, 0, stream>>>(keys, stat_g, out, n_rows);
}